// Round 5
// baseline (307.828 us; speedup 1.0000x reference)
//
#include <hip/hip_runtime.h>
#include <stdint.h>

#define HEADS 16
#define HD    64
#define SEQ   2048
#define BATCH 2
#define EMB   1024

using short8  = __attribute__((ext_vector_type(8))) short;
using float4v = __attribute__((ext_vector_type(4))) float;

// round-half-up f32 -> bf16 (2 VALU ops); inputs never NaN/overflow here
__device__ __forceinline__ unsigned int f2bfr(float f) {
    return (__float_as_uint(f) + 0x8000u) >> 16;
}

// swap with lane^1 (quad_perm [1,0,3,2])
__device__ __forceinline__ unsigned int dpp_xor1(unsigned int x) {
    return (unsigned int)__builtin_amdgcn_update_dpp(0, (int)x, 0xB1, 0xF, 0xF, true);
}

// ---------------- QKV projection (MFMA) + Wo convert ----------------
// z=0: queries->Qp (B,H,S,D) [pre-scaled by 0.125*log2e via Wq]
// z=1: keys->Kp (B,H,S,D)    z=2: values->Vt (B,H,D,S)   z=3: Wo->Wob (bf16)
__global__ __launch_bounds__(256) void proj_kernel(
    const float* __restrict__ Vx, const float* __restrict__ Kx, const float* __restrict__ Qx,
    const float* __restrict__ Wv, const float* __restrict__ Wk, const float* __restrict__ Wq,
    const float* __restrict__ Wo,
    unsigned short* __restrict__ Qp, unsigned short* __restrict__ Kp,
    unsigned short* __restrict__ Vt, unsigned short* __restrict__ Wob) {
    __shared__ __align__(16) unsigned short Ws[64 * 72];   // B-frag: Ws[e][d]
    __shared__ __align__(16) unsigned short xs[64 * 72];   // A-frag: xs[s][d]; reused for repack
    __shared__ __align__(16) unsigned short vt2[64 * 72];  // z==2 transpose buffer [e][s]

    const int t = threadIdx.x, w = t >> 6, lane = t & 63, cl = lane & 15, quad = lane >> 4;
    const int z  = blockIdx.z;
    const int bh = blockIdx.y;
    const int b  = bh >> 4, h = bh & 15;
    const int s0 = blockIdx.x * 64;

    if (z == 3) {
        // convert 1024 floats of Wo per block
        int idx = (bh * 32 + blockIdx.x) * 1024 + t * 4;
        float4 v = *(const float4*)(Wo + idx);
        uint2 o;
        o.x = f2bfr(v.x) | (f2bfr(v.y) << 16);
        o.y = f2bfr(v.z) | (f2bfr(v.w) << 16);
        *(uint2*)(Wob + idx) = o;
        return;
    }

    const float* x = (z == 0) ? Qx : (z == 1) ? Kx : Vx;
    const float* W = (z == 0) ? Wq : (z == 1) ? Wk : Wv;
    const float scale = (z == 0) ? 0.18033688011112044f : 1.0f;  // 0.125*log2(e)

#pragma unroll
    for (int rep = 0; rep < 4; ++rep) {
        int idx = rep * 1024 + t * 4;
        int e = idx >> 6, d0 = idx & 63;
        float4 w4 = *(const float4*)(W + idx);
        uint2 pk;
        pk.x = f2bfr(w4.x * scale) | (f2bfr(w4.y * scale) << 16);
        pk.y = f2bfr(w4.z * scale) | (f2bfr(w4.w * scale) << 16);
        *(uint2*)(&Ws[e * 72 + d0]) = pk;

        int s = e;
        float4 v4 = *(const float4*)(x + (size_t)(b * SEQ + s0 + s) * EMB + h * 64 + d0);
        uint2 px;
        px.x = f2bfr(v4.x) | (f2bfr(v4.y) << 16);
        px.y = f2bfr(v4.z) | (f2bfr(v4.w) << 16);
        *(uint2*)(&xs[s * 72 + d0]) = px;
    }
    __syncthreads();

    short8 a0 = *(const short8*)(&xs[(w * 16 + cl) * 72 + quad * 8]);
    short8 a1 = *(const short8*)(&xs[(w * 16 + cl) * 72 + 32 + quad * 8]);
    float4v c[4];
#pragma unroll
    for (int nt = 0; nt < 4; ++nt) c[nt] = (float4v){0.f, 0.f, 0.f, 0.f};
#pragma unroll
    for (int nt = 0; nt < 4; ++nt) {
        short8 b0 = *(const short8*)(&Ws[(nt * 16 + cl) * 72 + quad * 8]);
        c[nt] = __builtin_amdgcn_mfma_f32_16x16x32_bf16(a0, b0, c[nt], 0, 0, 0);
        short8 b1 = *(const short8*)(&Ws[(nt * 16 + cl) * 72 + 32 + quad * 8]);
        c[nt] = __builtin_amdgcn_mfma_f32_16x16x32_bf16(a1, b1, c[nt], 0, 0, 0);
    }

    if (z < 2) {
#pragma unroll
        for (int nt = 0; nt < 4; ++nt)
#pragma unroll
            for (int r = 0; r < 4; ++r)
                xs[(w * 16 + quad * 4 + r) * 72 + nt * 16 + cl] =
                    (unsigned short)f2bfr(c[nt][r]);
        unsigned short* outp = (z == 0) ? Qp : Kp;
        int sl = w * 16 + (lane >> 2), c0 = (lane & 3) * 16;
        uint4 o0 = *(const uint4*)(&xs[sl * 72 + c0]);
        uint4 o1 = *(const uint4*)(&xs[sl * 72 + c0 + 8]);
        size_t base = ((size_t)bh * SEQ + s0 + sl) * 64 + c0;
        *(uint4*)(outp + base)     = o0;
        *(uint4*)(outp + base + 8) = o1;
    } else {
#pragma unroll
        for (int nt = 0; nt < 4; ++nt)
#pragma unroll
            for (int r = 0; r < 4; ++r)
                vt2[(nt * 16 + cl) * 72 + w * 16 + quad * 4 + r] =
                    (unsigned short)f2bfr(c[nt][r]);
        __syncthreads();
        int e = t >> 2, sc0 = (t & 3) * 16;
        uint4 o0 = *(const uint4*)(&vt2[e * 72 + sc0]);
        uint4 o1 = *(const uint4*)(&vt2[e * 72 + sc0 + 8]);
        size_t base = ((size_t)bh * 64 + e) * SEQ + s0 + sc0;
        *(uint4*)(Vt + base)     = o0;
        *(uint4*)(Vt + base + 8) = o1;
    }
}

// ---------------- flash attention, barrier-free ----------------
// K/V B-fragments loaded DIRECTLY from global (16B contiguous in both layouts;
// chunk working set is L1/L2 resident). LDS holds only the wave-private P
// round-trip. No __syncthreads anywhere in the K-loop.
__global__ __launch_bounds__(256, 2) void attn_kernel(
    const unsigned short* __restrict__ Qp, const unsigned short* __restrict__ Kp,
    const unsigned short* __restrict__ Vt, unsigned short* __restrict__ AO) {
    __shared__ __align__(16) unsigned short Ps[4][32 * 72];   // per-wave [qrow(32)][key]

    const int t = threadIdx.x;
    const int w = t >> 6, lane = t & 63, cl = lane & 15, quad = lane >> 4;
    const int bh = blockIdx.x;           // bh on x: co-resident blocks share head
    const int q0 = blockIdx.y * 128;
    const size_t hbase = (size_t)bh * SEQ * 64;
    const unsigned short* Kbase = Kp + hbase;
    const unsigned short* Vbase = Vt + hbase;

    short8 aq[2][2];
#pragma unroll
    for (int qt = 0; qt < 2; ++qt) {
        size_t rbase = hbase + (size_t)(q0 + w * 32 + qt * 16 + cl) * 64 + quad * 8;
        aq[qt][0] = *(const short8*)(Qp + rbase);
        aq[qt][1] = *(const short8*)(Qp + rbase + 32);
    }

    short8 ones;
#pragma unroll
    for (int i = 0; i < 8; ++i) ones[i] = (short)0x3F80;  // bf16 1.0

    float4v acc[2][5];  // per q-tile: 4 O tiles + 1 row-sum tile
#pragma unroll
    for (int qt = 0; qt < 2; ++qt)
#pragma unroll
        for (int nt = 0; nt < 5; ++nt) acc[qt][nt] = (float4v){0.f, 0.f, 0.f, 0.f};

    const int even = ((lane & 1) == 0);
    const unsigned int psel = even ? 0x03020706u : 0x07060302u;  // v_perm selector
    // bank-spread offsets: even lanes -> nt{0,2} blocks, odd -> nt{1,3}
    const int evoff = even ? 0 : 8;
    unsigned int* Pw = (unsigned int*)Ps[w];

    // per-lane global offsets for K/V B-frag loads
    const unsigned short* kptr = Kbase + (size_t)(cl * 64 + quad * 8);
    const unsigned short* vptr = Vbase + (size_t)cl * SEQ + quad * 8;

#pragma unroll 2
    for (int kc = 0; kc < SEQ / 64; ++kc) {
        // issue all 16 B-frag loads up front (VMEM pipe; L1/L2 resident)
        short8 kf[4][2], vf[4][2];
#pragma unroll
        for (int nt = 0; nt < 4; ++nt) {
#pragma unroll
            for (int s2 = 0; s2 < 2; ++s2) {
                kf[nt][s2] = *(const short8*)(kptr + (size_t)(kc * 64 + nt * 16) * 64 + s2 * 32);
                vf[nt][s2] = *(const short8*)(vptr + (size_t)(nt * 16) * SEQ + kc * 64 + s2 * 32);
            }
        }

        // scores for both q-tiles
        float4v c[2][4];
#pragma unroll
        for (int qt = 0; qt < 2; ++qt)
#pragma unroll
            for (int nt = 0; nt < 4; ++nt) c[qt][nt] = (float4v){0.f, 0.f, 0.f, 0.f};
#pragma unroll
        for (int nt = 0; nt < 4; ++nt) {
            c[0][nt] = __builtin_amdgcn_mfma_f32_16x16x32_bf16(aq[0][0], kf[nt][0], c[0][nt], 0, 0, 0);
            c[0][nt] = __builtin_amdgcn_mfma_f32_16x16x32_bf16(aq[0][1], kf[nt][1], c[0][nt], 0, 0, 0);
            c[1][nt] = __builtin_amdgcn_mfma_f32_16x16x32_bf16(aq[1][0], kf[nt][0], c[1][nt], 0, 0, 0);
            c[1][nt] = __builtin_amdgcn_mfma_f32_16x16x32_bf16(aq[1][1], kf[nt][1], c[1][nt], 0, 0, 0);
        }

        // p = exp2(s); pack col-pairs into dwords via DPP + v_perm
#pragma unroll
        for (int qt = 0; qt < 2; ++qt) {
#pragma unroll
            for (int r = 0; r < 4; ++r) {
                unsigned int rr[4], wd[4];
#pragma unroll
                for (int nt = 0; nt < 4; ++nt)
                    rr[nt] = __float_as_uint(__builtin_amdgcn_exp2f(c[qt][nt][r])) + 0x8000u;
#pragma unroll
                for (int nt = 0; nt < 4; ++nt) {
                    unsigned int nb = dpp_xor1(rr[nt]);
                    wd[nt] = __builtin_amdgcn_perm(rr[nt], nb, psel);
                }
                unsigned int wa = even ? wd[0] : wd[1];
                unsigned int wb = even ? wd[2] : wd[3];
                int dwbase = (qt * 16 + quad * 4 + r) * 36 + evoff + (cl >> 1);
                Pw[dwbase]      = wa;
                Pw[dwbase + 16] = wb;
            }
        }

        // O += P*V ; l += P*ones  (Ps wave-private: in-wave lgkm ordering suffices)
#pragma unroll
        for (int s2i = 0; s2i < 2; ++s2i) {
            short8 ap0 = *(const short8*)(&Ps[w][cl * 72 + s2i * 32 + quad * 8]);
            short8 ap1 = *(const short8*)(&Ps[w][(16 + cl) * 72 + s2i * 32 + quad * 8]);
#pragma unroll
            for (int nt = 0; nt < 4; ++nt) {
                acc[0][nt] = __builtin_amdgcn_mfma_f32_16x16x32_bf16(ap0, vf[nt][s2i], acc[0][nt], 0, 0, 0);
                acc[1][nt] = __builtin_amdgcn_mfma_f32_16x16x32_bf16(ap1, vf[nt][s2i], acc[1][nt], 0, 0, 0);
            }
            acc[0][4] = __builtin_amdgcn_mfma_f32_16x16x32_bf16(ap0, ones, acc[0][4], 0, 0, 0);
            acc[1][4] = __builtin_amdgcn_mfma_f32_16x16x32_bf16(ap1, ones, acc[1][4], 0, 0, 0);
        }
    }

#pragma unroll
    for (int qt = 0; qt < 2; ++qt) {
        float inv[4];
#pragma unroll
        for (int r = 0; r < 4; ++r) inv[r] = 1.0f / acc[qt][4][r];
#pragma unroll
        for (int nt = 0; nt < 4; ++nt) {
#pragma unroll
            for (int r = 0; r < 4; ++r) {
                int row = q0 + w * 32 + qt * 16 + quad * 4 + r;
                AO[hbase + (size_t)row * 64 + nt * 16 + cl] =
                    (unsigned short)f2bfr(acc[qt][nt][r] * inv[r]);
            }
        }
    }
}

// ---------------- output projection: out = AO @ Wob^T + bo ----------------
__global__ __launch_bounds__(256) void outproj_kernel(
    const unsigned short* __restrict__ AO, const unsigned short* __restrict__ Wob,
    const float* __restrict__ bo, float* __restrict__ out) {
    __shared__ __align__(16) unsigned short As[2][64 * 72];
    __shared__ __align__(16) unsigned short Bs[2][64 * 72];

    const int t = threadIdx.x, w = t >> 6, lane = t & 63, cl = lane & 15, quad = lane >> 4;
    const int e0 = blockIdx.x * 64;
    const int m0 = blockIdx.y * 64;
    const int srow = t >> 3, scol = (t & 7) * 8;

    float4v c[4];
#pragma unroll
    for (int nt = 0; nt < 4; ++nt) c[nt] = (float4v){0.f, 0.f, 0.f, 0.f};

    uint4 areg[2], breg[2];
#pragma unroll
    for (int p = 0; p < 2; ++p) {
        int i = srow + p * 32;
        int r = m0 + i, b = r >> 11, s = r & 2047;
        areg[p] = *(const uint4*)(AO + ((size_t)(b * 16 + 0) * SEQ + s) * 64 + scol);
        breg[p] = *(const uint4*)(Wob + (size_t)(e0 + i) * EMB + scol);
    }

    for (int hc = 0; hc < 16; ++hc) {
        const int buf = hc & 1;
#pragma unroll
        for (int p = 0; p < 2; ++p) {
            int i = srow + p * 32;
            *(uint4*)(&As[buf][i * 72 + scol]) = areg[p];
            *(uint4*)(&Bs[buf][i * 72 + scol]) = breg[p];
        }
        __syncthreads();
        if (hc + 1 < 16) {
#pragma unroll
            for (int p = 0; p < 2; ++p) {
                int i = srow + p * 32;
                int r = m0 + i, b = r >> 11, s = r & 2047;
                areg[p] = *(const uint4*)(AO + ((size_t)(b * 16 + hc + 1) * SEQ + s) * 64 + scol);
                breg[p] = *(const uint4*)(Wob + (size_t)(e0 + i) * EMB + (hc + 1) * 64 + scol);
            }
        }
#pragma unroll
        for (int s2i = 0; s2i < 2; ++s2i) {
            short8 a = *(const short8*)(&As[buf][(w * 16 + cl) * 72 + s2i * 32 + quad * 8]);
#pragma unroll
            for (int nt = 0; nt < 4; ++nt) {
                short8 bb = *(const short8*)(&Bs[buf][(nt * 16 + cl) * 72 + s2i * 32 + quad * 8]);
                c[nt] = __builtin_amdgcn_mfma_f32_16x16x32_bf16(a, bb, c[nt], 0, 0, 0);
            }
        }
    }

#pragma unroll
    for (int nt = 0; nt < 4; ++nt) {
        float bias = bo[e0 + nt * 16 + cl];
#pragma unroll
        for (int r = 0; r < 4; ++r) {
            int row = m0 + w * 16 + quad * 4 + r;
            out[(size_t)row * EMB + e0 + nt * 16 + cl] = c[nt][r] + bias;
        }
    }
}

extern "C" void kernel_launch(void* const* d_in, const int* in_sizes, int n_in,
                              void* d_out, int out_size, void* d_ws, size_t ws_size,
                              hipStream_t stream) {
    const float* values  = (const float*)d_in[0];
    const float* keys    = (const float*)d_in[1];
    const float* queries = (const float*)d_in[2];
    const float* Wv = (const float*)d_in[3];
    const float* Wk = (const float*)d_in[4];
    const float* Wq = (const float*)d_in[5];
    const float* Wo = (const float*)d_in[6];
    const float* bo = (const float*)d_in[7];
    float* out = (float*)d_out;

    char* ws = (char*)d_ws;
    unsigned short* Qp  = (unsigned short*)(ws);                 // 8 MB (B,H,S,D)
    unsigned short* Kp  = (unsigned short*)(ws + (8u  << 20));   // 8 MB (B,H,S,D)
    unsigned short* Vt  = (unsigned short*)(ws + (16u << 20));   // 8 MB (B,H,D,S)
    unsigned short* AO  = (unsigned short*)(ws + (24u << 20));   // 8 MB (B,H,S,D)
    unsigned short* Wob = (unsigned short*)(ws + (32u << 20));   // 2 MB [e][k]

    proj_kernel<<<dim3(SEQ / 64, BATCH * HEADS, 4), dim3(256), 0, stream>>>(
        values, keys, queries, Wv, Wk, Wq, Wo, Qp, Kp, Vt, Wob);
    attn_kernel<<<dim3(BATCH * HEADS, SEQ / 128), dim3(256), 0, stream>>>(Qp, Kp, Vt, AO);
    outproj_kernel<<<dim3(EMB / 64, (BATCH * SEQ) / 64), dim3(256), 0, stream>>>(
        AO, Wob, bo, out);
}

// Round 6
// 293.010 us; speedup vs baseline: 1.0506x; 1.0506x over previous
//
#include <hip/hip_runtime.h>
#include <stdint.h>

#define HEADS 16
#define HD    64
#define SEQ   2048
#define BATCH 2
#define EMB   1024

using short8  = __attribute__((ext_vector_type(8))) short;
using float4v = __attribute__((ext_vector_type(4))) float;

// round-half-up f32 -> bf16 (2 VALU ops); inputs never NaN/overflow here
__device__ __forceinline__ unsigned int f2bfr(float f) {
    return (__float_as_uint(f) + 0x8000u) >> 16;
}

// swap with lane^1 (quad_perm [1,0,3,2])
__device__ __forceinline__ unsigned int dpp_xor1(unsigned int x) {
    return (unsigned int)__builtin_amdgcn_update_dpp(0, (int)x, 0xB1, 0xF, 0xF, true);
}

// key -> slot permutation (pair-major): slot = [k3 k2 k1 | k5 k4 | k0]
__device__ __forceinline__ int keyslot(int k) {
    return ((k & 14) << 2) | ((k >> 4) << 1) | (k & 1);
}

// ---------------- QKV projection (MFMA) + Wo convert ----------------
// z=0: queries->Qp (B,H,S,D) [pre-scaled by 0.125*log2e via Wq]
// z=1: keys->Kp (B,H,S,D)    z=2: values->Vt (B,H,D,S) with slot-permuted keys
// z=3: Wo->Wob (bf16)
__global__ __launch_bounds__(256) void proj_kernel(
    const float* __restrict__ Vx, const float* __restrict__ Kx, const float* __restrict__ Qx,
    const float* __restrict__ Wv, const float* __restrict__ Wk, const float* __restrict__ Wq,
    const float* __restrict__ Wo,
    unsigned short* __restrict__ Qp, unsigned short* __restrict__ Kp,
    unsigned short* __restrict__ Vt, unsigned short* __restrict__ Wob) {
    __shared__ __align__(16) unsigned short Ws[64 * 72];   // B-frag: Ws[e][d]
    __shared__ __align__(16) unsigned short xs[64 * 72];   // A-frag: xs[s][d]; reused for repack
    __shared__ __align__(16) unsigned short vt2[64 * 72];  // z==2 transpose buffer [e][slot]

    const int t = threadIdx.x, w = t >> 6, lane = t & 63, cl = lane & 15, quad = lane >> 4;
    const int z  = blockIdx.z;
    const int bh = blockIdx.y;
    const int b  = bh >> 4, h = bh & 15;
    const int s0 = blockIdx.x * 64;

    if (z == 3) {
        int idx = (bh * 32 + blockIdx.x) * 1024 + t * 4;
        float4 v = *(const float4*)(Wo + idx);
        uint2 o;
        o.x = f2bfr(v.x) | (f2bfr(v.y) << 16);
        o.y = f2bfr(v.z) | (f2bfr(v.w) << 16);
        *(uint2*)(Wob + idx) = o;
        return;
    }

    const float* x = (z == 0) ? Qx : (z == 1) ? Kx : Vx;
    const float* W = (z == 0) ? Wq : (z == 1) ? Wk : Wv;
    const float scale = (z == 0) ? 0.18033688011112044f : 1.0f;  // 0.125*log2(e)

#pragma unroll
    for (int rep = 0; rep < 4; ++rep) {
        int idx = rep * 1024 + t * 4;
        int e = idx >> 6, d0 = idx & 63;
        float4 w4 = *(const float4*)(W + idx);
        uint2 pk;
        pk.x = f2bfr(w4.x * scale) | (f2bfr(w4.y * scale) << 16);
        pk.y = f2bfr(w4.z * scale) | (f2bfr(w4.w * scale) << 16);
        *(uint2*)(&Ws[e * 72 + d0]) = pk;

        int s = e;
        float4 v4 = *(const float4*)(x + (size_t)(b * SEQ + s0 + s) * EMB + h * 64 + d0);
        uint2 px;
        px.x = f2bfr(v4.x) | (f2bfr(v4.y) << 16);
        px.y = f2bfr(v4.z) | (f2bfr(v4.w) << 16);
        *(uint2*)(&xs[s * 72 + d0]) = px;
    }
    __syncthreads();

    short8 a0 = *(const short8*)(&xs[(w * 16 + cl) * 72 + quad * 8]);
    short8 a1 = *(const short8*)(&xs[(w * 16 + cl) * 72 + 32 + quad * 8]);
    float4v c[4];
#pragma unroll
    for (int nt = 0; nt < 4; ++nt) c[nt] = (float4v){0.f, 0.f, 0.f, 0.f};
#pragma unroll
    for (int nt = 0; nt < 4; ++nt) {
        short8 b0 = *(const short8*)(&Ws[(nt * 16 + cl) * 72 + quad * 8]);
        c[nt] = __builtin_amdgcn_mfma_f32_16x16x32_bf16(a0, b0, c[nt], 0, 0, 0);
        short8 b1 = *(const short8*)(&Ws[(nt * 16 + cl) * 72 + 32 + quad * 8]);
        c[nt] = __builtin_amdgcn_mfma_f32_16x16x32_bf16(a1, b1, c[nt], 0, 0, 0);
    }

    if (z < 2) {
#pragma unroll
        for (int nt = 0; nt < 4; ++nt)
#pragma unroll
            for (int r = 0; r < 4; ++r)
                xs[(w * 16 + quad * 4 + r) * 72 + nt * 16 + cl] =
                    (unsigned short)f2bfr(c[nt][r]);
        unsigned short* outp = (z == 0) ? Qp : Kp;
        int sl = w * 16 + (lane >> 2), c0 = (lane & 3) * 16;
        uint4 o0 = *(const uint4*)(&xs[sl * 72 + c0]);
        uint4 o1 = *(const uint4*)(&xs[sl * 72 + c0 + 8]);
        size_t base = ((size_t)bh * SEQ + s0 + sl) * 64 + c0;
        *(uint4*)(outp + base)     = o0;
        *(uint4*)(outp + base + 8) = o1;
    } else {
        // transpose + key->slot permute, then coalesced store (B,H,D,S_slots)
#pragma unroll
        for (int nt = 0; nt < 4; ++nt)
#pragma unroll
            for (int r = 0; r < 4; ++r) {
                int s = w * 16 + quad * 4 + r;
                vt2[(nt * 16 + cl) * 72 + keyslot(s)] = (unsigned short)f2bfr(c[nt][r]);
            }
        __syncthreads();
        int e = t >> 2, sc0 = (t & 3) * 16;
        uint4 o0 = *(const uint4*)(&vt2[e * 72 + sc0]);
        uint4 o1 = *(const uint4*)(&vt2[e * 72 + sc0 + 8]);
        size_t base = ((size_t)bh * 64 + e) * SEQ + s0 + sc0;
        *(uint4*)(Vt + base)     = o0;
        *(uint4*)(Vt + base + 8) = o1;
    }
}

// ---------------- flash attention, BQ=128, single-buffer LDS ----------------
// LDS 36.9 KB -> 4 blocks/CU (16 waves) for cross-block barrier hiding.
// P stored pair-major (slot order); V slot-permuted to match.
__global__ __launch_bounds__(256, 4) void attn_kernel(
    const unsigned short* __restrict__ Qp, const unsigned short* __restrict__ Kp,
    const unsigned short* __restrict__ Vt, unsigned short* __restrict__ AO) {
    __shared__ __align__(16) unsigned short Ks[64 * 72];      // [key][d]
    __shared__ __align__(16) unsigned short Vs[64 * 72];      // [d][slot]
    __shared__ __align__(16) unsigned short Ps[4][32 * 72];   // per-wave [qrow][slot]

    const int t = threadIdx.x;
    const int w = t >> 6, lane = t & 63, cl = lane & 15, quad = lane >> 4;
    const int bh = blockIdx.y;
    const int q0 = blockIdx.x * 128;
    const size_t hbase = (size_t)bh * SEQ * 64;
    const unsigned short* Kbase = Kp + hbase;
    const unsigned short* Vbase = Vt + hbase;

    short8 aq[2][2];
#pragma unroll
    for (int qt = 0; qt < 2; ++qt) {
        size_t rbase = hbase + (size_t)(q0 + w * 32 + qt * 16 + cl) * 64 + quad * 8;
        aq[qt][0] = *(const short8*)(Qp + rbase);
        aq[qt][1] = *(const short8*)(Qp + rbase + 32);
    }

    short8 ones;
#pragma unroll
    for (int i = 0; i < 8; ++i) ones[i] = (short)0x3F80;  // bf16 1.0

    float4v acc[2][5];  // per q-tile: 4 O tiles + 1 row-sum tile
#pragma unroll
    for (int qt = 0; qt < 2; ++qt)
#pragma unroll
        for (int nt = 0; nt < 5; ++nt) acc[qt][nt] = (float4v){0.f, 0.f, 0.f, 0.f};

    const int srow = t >> 3;       // 0..31
    const int scol = (t & 7) * 8;  // 0..56

    uint4 kreg[2], vreg[2];
#pragma unroll
    for (int p = 0; p < 2; ++p) {
        int row = srow + p * 32;
        kreg[p] = *(const uint4*)(Kbase + row * 64 + scol);
        vreg[p] = *(const uint4*)(Vbase + (size_t)row * SEQ + scol);
    }

    const int even = ((lane & 1) == 0);
    const unsigned int psel = even ? 0x03020706u : 0x07060302u;
    const int p2 = (cl >> 1) * 2 + (even ? 0 : 1);  // uint2 offset within row
    uint2* Pw2 = (uint2*)Ps[w];

    for (int kc = 0; kc < SEQ / 64; ++kc) {
        *(uint4*)(&Ks[srow * 72 + scol])        = kreg[0];
        *(uint4*)(&Ks[(srow + 32) * 72 + scol]) = kreg[1];
        *(uint4*)(&Vs[srow * 72 + scol])        = vreg[0];
        *(uint4*)(&Vs[(srow + 32) * 72 + scol]) = vreg[1];
        __syncthreads();
        if (kc + 1 < SEQ / 64) {
#pragma unroll
            for (int p = 0; p < 2; ++p) {
                int row = srow + p * 32;
                kreg[p] = *(const uint4*)(Kbase + (size_t)(kc + 1) * 4096 + row * 64 + scol);
                vreg[p] = *(const uint4*)(Vbase + (size_t)row * SEQ + (kc + 1) * 64 + scol);
            }
        }

        // scores for both q-tiles; K B-frags read once
        float4v c[2][4];
#pragma unroll
        for (int qt = 0; qt < 2; ++qt)
#pragma unroll
            for (int nt = 0; nt < 4; ++nt) c[qt][nt] = (float4v){0.f, 0.f, 0.f, 0.f};
#pragma unroll
        for (int nt = 0; nt < 4; ++nt) {
            short8 bk0 = *(const short8*)(&Ks[(nt * 16 + cl) * 72 + quad * 8]);
            short8 bk1 = *(const short8*)(&Ks[(nt * 16 + cl) * 72 + 32 + quad * 8]);
            c[0][nt] = __builtin_amdgcn_mfma_f32_16x16x32_bf16(aq[0][0], bk0, c[0][nt], 0, 0, 0);
            c[0][nt] = __builtin_amdgcn_mfma_f32_16x16x32_bf16(aq[0][1], bk1, c[0][nt], 0, 0, 0);
            c[1][nt] = __builtin_amdgcn_mfma_f32_16x16x32_bf16(aq[1][0], bk0, c[1][nt], 0, 0, 0);
            c[1][nt] = __builtin_amdgcn_mfma_f32_16x16x32_bf16(aq[1][1], bk1, c[1][nt], 0, 0, 0);
        }

        // p = exp2(s); pack to pair-major slots, one b64 write per (qt,r)
#pragma unroll
        for (int qt = 0; qt < 2; ++qt) {
#pragma unroll
            for (int r = 0; r < 4; ++r) {
                unsigned int rr[4];
#pragma unroll
                for (int nt = 0; nt < 4; ++nt)
                    rr[nt] = __float_as_uint(__builtin_amdgcn_exp2f(c[qt][nt][r])) + 0x8000u;
                unsigned int g1 = dpp_xor1(even ? rr[2] : rr[0]);
                unsigned int g2 = dpp_xor1(even ? rr[3] : rr[1]);
                unsigned int s0 = even ? rr[0] : rr[2];
                unsigned int s1 = even ? rr[1] : rr[3];
                uint2 wd;
                wd.x = __builtin_amdgcn_perm(s0, g1, psel);
                wd.y = __builtin_amdgcn_perm(s1, g2, psel);
                int row = qt * 16 + quad * 4 + r;
                Pw2[row * 18 + p2] = wd;
            }
        }

        // O += P*V ; l += P*ones  (Ps wave-private: in-wave lgkm ordering suffices)
#pragma unroll
        for (int s2i = 0; s2i < 2; ++s2i) {
            short8 ap0 = *(const short8*)(&Ps[w][cl * 72 + s2i * 32 + quad * 8]);
            short8 ap1 = *(const short8*)(&Ps[w][(16 + cl) * 72 + s2i * 32 + quad * 8]);
#pragma unroll
            for (int nt = 0; nt < 4; ++nt) {
                short8 bv = *(const short8*)(&Vs[(nt * 16 + cl) * 72 + s2i * 32 + quad * 8]);
                acc[0][nt] = __builtin_amdgcn_mfma_f32_16x16x32_bf16(ap0, bv, acc[0][nt], 0, 0, 0);
                acc[1][nt] = __builtin_amdgcn_mfma_f32_16x16x32_bf16(ap1, bv, acc[1][nt], 0, 0, 0);
            }
            acc[0][4] = __builtin_amdgcn_mfma_f32_16x16x32_bf16(ap0, ones, acc[0][4], 0, 0, 0);
            acc[1][4] = __builtin_amdgcn_mfma_f32_16x16x32_bf16(ap1, ones, acc[1][4], 0, 0, 0);
        }
        __syncthreads();
    }

#pragma unroll
    for (int qt = 0; qt < 2; ++qt) {
        float inv[4];
#pragma unroll
        for (int r = 0; r < 4; ++r) inv[r] = 1.0f / acc[qt][4][r];
#pragma unroll
        for (int nt = 0; nt < 4; ++nt) {
#pragma unroll
            for (int r = 0; r < 4; ++r) {
                int row = q0 + w * 32 + qt * 16 + quad * 4 + r;
                AO[hbase + (size_t)row * 64 + nt * 16 + cl] =
                    (unsigned short)f2bfr(acc[qt][nt][r] * inv[r]);
            }
        }
    }
}

// ---------------- output projection: out = AO @ Wob^T + bo ----------------
// single-buffered LDS (18.4 KB) for high occupancy
__global__ __launch_bounds__(256) void outproj_kernel(
    const unsigned short* __restrict__ AO, const unsigned short* __restrict__ Wob,
    const float* __restrict__ bo, float* __restrict__ out) {
    __shared__ __align__(16) unsigned short As[64 * 72];
    __shared__ __align__(16) unsigned short Bs[64 * 72];

    const int t = threadIdx.x, w = t >> 6, lane = t & 63, cl = lane & 15, quad = lane >> 4;
    const int e0 = blockIdx.x * 64;
    const int m0 = blockIdx.y * 64;
    const int srow = t >> 3, scol = (t & 7) * 8;

    float4v c[4];
#pragma unroll
    for (int nt = 0; nt < 4; ++nt) c[nt] = (float4v){0.f, 0.f, 0.f, 0.f};

    uint4 areg[2], breg[2];
#pragma unroll
    for (int p = 0; p < 2; ++p) {
        int i = srow + p * 32;
        int r = m0 + i, b = r >> 11, s = r & 2047;
        areg[p] = *(const uint4*)(AO + ((size_t)(b * 16 + 0) * SEQ + s) * 64 + scol);
        breg[p] = *(const uint4*)(Wob + (size_t)(e0 + i) * EMB + scol);
    }

    for (int hc = 0; hc < 16; ++hc) {
#pragma unroll
        for (int p = 0; p < 2; ++p) {
            int i = srow + p * 32;
            *(uint4*)(&As[i * 72 + scol]) = areg[p];
            *(uint4*)(&Bs[i * 72 + scol]) = breg[p];
        }
        __syncthreads();
        if (hc + 1 < 16) {
#pragma unroll
            for (int p = 0; p < 2; ++p) {
                int i = srow + p * 32;
                int r = m0 + i, b = r >> 11, s = r & 2047;
                areg[p] = *(const uint4*)(AO + ((size_t)(b * 16 + hc + 1) * SEQ + s) * 64 + scol);
                breg[p] = *(const uint4*)(Wob + (size_t)(e0 + i) * EMB + (hc + 1) * 64 + scol);
            }
        }
#pragma unroll
        for (int s2i = 0; s2i < 2; ++s2i) {
            short8 a = *(const short8*)(&As[(w * 16 + cl) * 72 + s2i * 32 + quad * 8]);
#pragma unroll
            for (int nt = 0; nt < 4; ++nt) {
                short8 bb = *(const short8*)(&Bs[(nt * 16 + cl) * 72 + s2i * 32 + quad * 8]);
                c[nt] = __builtin_amdgcn_mfma_f32_16x16x32_bf16(a, bb, c[nt], 0, 0, 0);
            }
        }
        __syncthreads();
    }

#pragma unroll
    for (int nt = 0; nt < 4; ++nt) {
        float bias = bo[e0 + nt * 16 + cl];
#pragma unroll
        for (int r = 0; r < 4; ++r) {
            int row = m0 + w * 16 + quad * 4 + r;
            out[(size_t)row * EMB + e0 + nt * 16 + cl] = c[nt][r] + bias;
        }
    }
}

extern "C" void kernel_launch(void* const* d_in, const int* in_sizes, int n_in,
                              void* d_out, int out_size, void* d_ws, size_t ws_size,
                              hipStream_t stream) {
    const float* values  = (const float*)d_in[0];
    const float* keys    = (const float*)d_in[1];
    const float* queries = (const float*)d_in[2];
    const float* Wv = (const float*)d_in[3];
    const float* Wk = (const float*)d_in[4];
    const float* Wq = (const float*)d_in[5];
    const float* Wo = (const float*)d_in[6];
    const float* bo = (const float*)d_in[7];
    float* out = (float*)d_out;

    char* ws = (char*)d_ws;
    unsigned short* Qp  = (unsigned short*)(ws);                 // 8 MB (B,H,S,D)
    unsigned short* Kp  = (unsigned short*)(ws + (8u  << 20));   // 8 MB (B,H,S,D)
    unsigned short* Vt  = (unsigned short*)(ws + (16u << 20));   // 8 MB (B,H,D,S slots)
    unsigned short* AO  = (unsigned short*)(ws + (24u << 20));   // 8 MB (B,H,S,D)
    unsigned short* Wob = (unsigned short*)(ws + (32u << 20));   // 2 MB [e][k]

    proj_kernel<<<dim3(SEQ / 64, BATCH * HEADS, 4), dim3(256), 0, stream>>>(
        values, keys, queries, Wv, Wk, Wq, Wo, Qp, Kp, Vt, Wob);
    attn_kernel<<<dim3(SEQ / 128, BATCH * HEADS), dim3(256), 0, stream>>>(Qp, Kp, Vt, AO);
    outproj_kernel<<<dim3(EMB / 64, (BATCH * SEQ) / 64), dim3(256), 0, stream>>>(
        AO, Wob, bo, out);
}

// Round 7
// 267.590 us; speedup vs baseline: 1.1504x; 1.0950x over previous
//
#include <hip/hip_runtime.h>
#include <stdint.h>

#define HEADS 16
#define HD    64
#define SEQ   2048
#define BATCH 2
#define EMB   1024
#define KSPLIT 2

using short8  = __attribute__((ext_vector_type(8))) short;
using float4v = __attribute__((ext_vector_type(4))) float;

// round-half-up f32 -> bf16 (2 VALU ops); inputs never NaN/overflow here
__device__ __forceinline__ unsigned int f2bfr(float f) {
    return (__float_as_uint(f) + 0x8000u) >> 16;
}

// swap with lane^1 (quad_perm [1,0,3,2])
__device__ __forceinline__ unsigned int dpp_xor1(unsigned int x) {
    return (unsigned int)__builtin_amdgcn_update_dpp(0, (int)x, 0xB1, 0xF, 0xF, true);
}

// key -> slot permutation (pair-major): slot = [k3 k2 k1 | k5 k4 | k0]
__device__ __forceinline__ int keyslot(int k) {
    return ((k & 14) << 2) | ((k >> 4) << 1) | (k & 1);
}

// ---------------- QKV projection (MFMA) + Wo convert ----------------
// z=0: queries->Qp (B,H,S,D) [pre-scaled by 0.125*log2e via Wq]
// z=1: keys->Kp (B,H,S,D)    z=2: values->Vt (B,H,D,S) with slot-permuted keys
// z=3: Wo->Wob (bf16)
__global__ __launch_bounds__(256) void proj_kernel(
    const float* __restrict__ Vx, const float* __restrict__ Kx, const float* __restrict__ Qx,
    const float* __restrict__ Wv, const float* __restrict__ Wk, const float* __restrict__ Wq,
    const float* __restrict__ Wo,
    unsigned short* __restrict__ Qp, unsigned short* __restrict__ Kp,
    unsigned short* __restrict__ Vt, unsigned short* __restrict__ Wob) {
    __shared__ __align__(16) unsigned short Ws[64 * 72];   // B-frag: Ws[e][d]
    __shared__ __align__(16) unsigned short xs[64 * 72];   // A-frag: xs[s][d]; reused for repack
    __shared__ __align__(16) unsigned short vt2[64 * 72];  // z==2 transpose buffer [e][slot]

    const int t = threadIdx.x, w = t >> 6, lane = t & 63, cl = lane & 15, quad = lane >> 4;
    const int z  = blockIdx.z;
    const int bh = blockIdx.y;
    const int b  = bh >> 4, h = bh & 15;
    const int s0 = blockIdx.x * 64;

    if (z == 3) {
        int idx = (bh * 32 + blockIdx.x) * 1024 + t * 4;
        float4 v = *(const float4*)(Wo + idx);
        uint2 o;
        o.x = f2bfr(v.x) | (f2bfr(v.y) << 16);
        o.y = f2bfr(v.z) | (f2bfr(v.w) << 16);
        *(uint2*)(Wob + idx) = o;
        return;
    }

    const float* x = (z == 0) ? Qx : (z == 1) ? Kx : Vx;
    const float* W = (z == 0) ? Wq : (z == 1) ? Wk : Wv;
    const float scale = (z == 0) ? 0.18033688011112044f : 1.0f;  // 0.125*log2(e)

#pragma unroll
    for (int rep = 0; rep < 4; ++rep) {
        int idx = rep * 1024 + t * 4;
        int e = idx >> 6, d0 = idx & 63;
        float4 w4 = *(const float4*)(W + idx);
        uint2 pk;
        pk.x = f2bfr(w4.x * scale) | (f2bfr(w4.y * scale) << 16);
        pk.y = f2bfr(w4.z * scale) | (f2bfr(w4.w * scale) << 16);
        *(uint2*)(&Ws[e * 72 + d0]) = pk;

        int s = e;
        float4 v4 = *(const float4*)(x + (size_t)(b * SEQ + s0 + s) * EMB + h * 64 + d0);
        uint2 px;
        px.x = f2bfr(v4.x) | (f2bfr(v4.y) << 16);
        px.y = f2bfr(v4.z) | (f2bfr(v4.w) << 16);
        *(uint2*)(&xs[s * 72 + d0]) = px;
    }
    __syncthreads();

    short8 a0 = *(const short8*)(&xs[(w * 16 + cl) * 72 + quad * 8]);
    short8 a1 = *(const short8*)(&xs[(w * 16 + cl) * 72 + 32 + quad * 8]);
    float4v c[4];
#pragma unroll
    for (int nt = 0; nt < 4; ++nt) c[nt] = (float4v){0.f, 0.f, 0.f, 0.f};
#pragma unroll
    for (int nt = 0; nt < 4; ++nt) {
        short8 b0 = *(const short8*)(&Ws[(nt * 16 + cl) * 72 + quad * 8]);
        c[nt] = __builtin_amdgcn_mfma_f32_16x16x32_bf16(a0, b0, c[nt], 0, 0, 0);
        short8 b1 = *(const short8*)(&Ws[(nt * 16 + cl) * 72 + 32 + quad * 8]);
        c[nt] = __builtin_amdgcn_mfma_f32_16x16x32_bf16(a1, b1, c[nt], 0, 0, 0);
    }

    if (z < 2) {
#pragma unroll
        for (int nt = 0; nt < 4; ++nt)
#pragma unroll
            for (int r = 0; r < 4; ++r)
                xs[(w * 16 + quad * 4 + r) * 72 + nt * 16 + cl] =
                    (unsigned short)f2bfr(c[nt][r]);
        unsigned short* outp = (z == 0) ? Qp : Kp;
        int sl = w * 16 + (lane >> 2), c0 = (lane & 3) * 16;
        uint4 o0 = *(const uint4*)(&xs[sl * 72 + c0]);
        uint4 o1 = *(const uint4*)(&xs[sl * 72 + c0 + 8]);
        size_t base = ((size_t)bh * SEQ + s0 + sl) * 64 + c0;
        *(uint4*)(outp + base)     = o0;
        *(uint4*)(outp + base + 8) = o1;
    } else {
        // transpose + key->slot permute, then coalesced store (B,H,D,S_slots)
#pragma unroll
        for (int nt = 0; nt < 4; ++nt)
#pragma unroll
            for (int r = 0; r < 4; ++r) {
                int s = w * 16 + quad * 4 + r;
                vt2[(nt * 16 + cl) * 72 + keyslot(s)] = (unsigned short)f2bfr(c[nt][r]);
            }
        __syncthreads();
        int e = t >> 2, sc0 = (t & 3) * 16;
        uint4 o0 = *(const uint4*)(&vt2[e * 72 + sc0]);
        uint4 o1 = *(const uint4*)(&vt2[e * 72 + sc0 + 8]);
        size_t base = ((size_t)bh * 64 + e) * SEQ + s0 + sc0;
        *(uint4*)(Vt + base)     = o0;
        *(uint4*)(Vt + base + 8) = o1;
    }
}

// ---------------- flash attention, BQ=128, KSPLIT partial accumulation --------
// Fixed-offset softmax (no running max) => key-range partials combine by plain
// addition. blockIdx.z = key-slice; each block does SEQ/64/KSPLIT chunks and
// writes unnormalized bf16 O-partials + fp32 l-partials.
__global__ __launch_bounds__(256, 4) void attn_kernel(
    const unsigned short* __restrict__ Qp, const unsigned short* __restrict__ Kp,
    const unsigned short* __restrict__ Vt,
    unsigned short* __restrict__ Opart, float* __restrict__ Lpart) {
    __shared__ __align__(16) unsigned short Ks[64 * 72];      // [key][d]
    __shared__ __align__(16) unsigned short Vs[64 * 72];      // [d][slot]
    __shared__ __align__(16) unsigned short Ps[4][32 * 72];   // per-wave [qrow][slot]

    const int t = threadIdx.x;
    const int w = t >> 6, lane = t & 63, cl = lane & 15, quad = lane >> 4;
    const int bh = blockIdx.y;
    const int q0 = blockIdx.x * 128;
    const int ks = blockIdx.z;
    const int kc0 = ks * (SEQ / 64 / KSPLIT);
    const int kc1 = kc0 + (SEQ / 64 / KSPLIT);
    const size_t hbase = (size_t)bh * SEQ * 64;
    const unsigned short* Kbase = Kp + hbase;
    const unsigned short* Vbase = Vt + hbase;

    short8 aq[2][2];
#pragma unroll
    for (int qt = 0; qt < 2; ++qt) {
        size_t rbase = hbase + (size_t)(q0 + w * 32 + qt * 16 + cl) * 64 + quad * 8;
        aq[qt][0] = *(const short8*)(Qp + rbase);
        aq[qt][1] = *(const short8*)(Qp + rbase + 32);
    }

    short8 ones;
#pragma unroll
    for (int i = 0; i < 8; ++i) ones[i] = (short)0x3F80;  // bf16 1.0

    float4v acc[2][5];  // per q-tile: 4 O tiles + 1 row-sum tile
#pragma unroll
    for (int qt = 0; qt < 2; ++qt)
#pragma unroll
        for (int nt = 0; nt < 5; ++nt) acc[qt][nt] = (float4v){0.f, 0.f, 0.f, 0.f};

    const int srow = t >> 3;       // 0..31
    const int scol = (t & 7) * 8;  // 0..56

    uint4 kreg[2], vreg[2];
#pragma unroll
    for (int p = 0; p < 2; ++p) {
        int row = srow + p * 32;
        kreg[p] = *(const uint4*)(Kbase + (size_t)kc0 * 4096 + row * 64 + scol);
        vreg[p] = *(const uint4*)(Vbase + (size_t)row * SEQ + kc0 * 64 + scol);
    }

    const int even = ((lane & 1) == 0);
    const unsigned int psel = even ? 0x03020706u : 0x07060302u;
    const int p2 = (cl >> 1) * 2 + (even ? 0 : 1);  // uint2 offset within row
    uint2* Pw2 = (uint2*)Ps[w];

    for (int kc = kc0; kc < kc1; ++kc) {
        *(uint4*)(&Ks[srow * 72 + scol])        = kreg[0];
        *(uint4*)(&Ks[(srow + 32) * 72 + scol]) = kreg[1];
        *(uint4*)(&Vs[srow * 72 + scol])        = vreg[0];
        *(uint4*)(&Vs[(srow + 32) * 72 + scol]) = vreg[1];
        __syncthreads();
        if (kc + 1 < kc1) {
#pragma unroll
            for (int p = 0; p < 2; ++p) {
                int row = srow + p * 32;
                kreg[p] = *(const uint4*)(Kbase + (size_t)(kc + 1) * 4096 + row * 64 + scol);
                vreg[p] = *(const uint4*)(Vbase + (size_t)row * SEQ + (kc + 1) * 64 + scol);
            }
        }

        // scores for both q-tiles; K B-frags read once
        float4v c[2][4];
#pragma unroll
        for (int qt = 0; qt < 2; ++qt)
#pragma unroll
            for (int nt = 0; nt < 4; ++nt) c[qt][nt] = (float4v){0.f, 0.f, 0.f, 0.f};
#pragma unroll
        for (int nt = 0; nt < 4; ++nt) {
            short8 bk0 = *(const short8*)(&Ks[(nt * 16 + cl) * 72 + quad * 8]);
            short8 bk1 = *(const short8*)(&Ks[(nt * 16 + cl) * 72 + 32 + quad * 8]);
            c[0][nt] = __builtin_amdgcn_mfma_f32_16x16x32_bf16(aq[0][0], bk0, c[0][nt], 0, 0, 0);
            c[0][nt] = __builtin_amdgcn_mfma_f32_16x16x32_bf16(aq[0][1], bk1, c[0][nt], 0, 0, 0);
            c[1][nt] = __builtin_amdgcn_mfma_f32_16x16x32_bf16(aq[1][0], bk0, c[1][nt], 0, 0, 0);
            c[1][nt] = __builtin_amdgcn_mfma_f32_16x16x32_bf16(aq[1][1], bk1, c[1][nt], 0, 0, 0);
        }

        // p = exp2(s); pack to pair-major slots, one b64 write per (qt,r)
#pragma unroll
        for (int qt = 0; qt < 2; ++qt) {
#pragma unroll
            for (int r = 0; r < 4; ++r) {
                unsigned int rr[4];
#pragma unroll
                for (int nt = 0; nt < 4; ++nt)
                    rr[nt] = __float_as_uint(__builtin_amdgcn_exp2f(c[qt][nt][r])) + 0x8000u;
                unsigned int g1 = dpp_xor1(even ? rr[2] : rr[0]);
                unsigned int g2 = dpp_xor1(even ? rr[3] : rr[1]);
                unsigned int s0 = even ? rr[0] : rr[2];
                unsigned int s1 = even ? rr[1] : rr[3];
                uint2 wd;
                wd.x = __builtin_amdgcn_perm(s0, g1, psel);
                wd.y = __builtin_amdgcn_perm(s1, g2, psel);
                int row = qt * 16 + quad * 4 + r;
                Pw2[row * 18 + p2] = wd;
            }
        }

        // O += P*V ; l += P*ones  (Ps wave-private: in-wave lgkm ordering suffices)
#pragma unroll
        for (int s2i = 0; s2i < 2; ++s2i) {
            short8 ap0 = *(const short8*)(&Ps[w][cl * 72 + s2i * 32 + quad * 8]);
            short8 ap1 = *(const short8*)(&Ps[w][(16 + cl) * 72 + s2i * 32 + quad * 8]);
#pragma unroll
            for (int nt = 0; nt < 4; ++nt) {
                short8 bv = *(const short8*)(&Vs[(nt * 16 + cl) * 72 + s2i * 32 + quad * 8]);
                acc[0][nt] = __builtin_amdgcn_mfma_f32_16x16x32_bf16(ap0, bv, acc[0][nt], 0, 0, 0);
                acc[1][nt] = __builtin_amdgcn_mfma_f32_16x16x32_bf16(ap1, bv, acc[1][nt], 0, 0, 0);
            }
            acc[0][4] = __builtin_amdgcn_mfma_f32_16x16x32_bf16(ap0, ones, acc[0][4], 0, 0, 0);
            acc[1][4] = __builtin_amdgcn_mfma_f32_16x16x32_bf16(ap1, ones, acc[1][4], 0, 0, 0);
        }
        __syncthreads();
    }

    // write unnormalized partials
    unsigned short* Op = Opart + (size_t)ks * (BATCH * HEADS * SEQ * 64);
    float* Lp = Lpart + (size_t)ks * (BATCH * HEADS * SEQ);
#pragma unroll
    for (int qt = 0; qt < 2; ++qt) {
#pragma unroll
        for (int nt = 0; nt < 4; ++nt) {
#pragma unroll
            for (int r = 0; r < 4; ++r) {
                int row = q0 + w * 32 + qt * 16 + quad * 4 + r;
                Op[hbase + (size_t)row * 64 + nt * 16 + cl] =
                    (unsigned short)f2bfr(acc[qt][nt][r]);
            }
        }
        if (cl == 0) {
#pragma unroll
            for (int r = 0; r < 4; ++r) {
                int row = q0 + w * 32 + qt * 16 + quad * 4 + r;
                Lp[(size_t)bh * SEQ + row] = acc[qt][4][r];
            }
        }
    }
}

// ---------------- normalize: AO = (O0+O1)/(l0+l1) ----------------
__global__ __launch_bounds__(256) void norm_kernel(
    const unsigned short* __restrict__ Opart, const float* __restrict__ Lpart,
    unsigned short* __restrict__ AO) {
    const int i = blockIdx.x * 256 + threadIdx.x;
    const int row = i >> 3;
    const int d0 = (i & 7) * 8;
    const size_t stride = (size_t)BATCH * HEADS * SEQ * 64;

    uint4 o0 = *(const uint4*)(Opart + (size_t)row * 64 + d0);
    uint4 o1 = *(const uint4*)(Opart + stride + (size_t)row * 64 + d0);
    float l = Lpart[row] + Lpart[BATCH * HEADS * SEQ + row];
    float inv = 1.0f / l;

    const unsigned int* a = (const unsigned int*)&o0;
    const unsigned int* b = (const unsigned int*)&o1;
    unsigned int res[4];
#pragma unroll
    for (int k = 0; k < 4; ++k) {
        float lo = __uint_as_float(a[k] << 16) + __uint_as_float(b[k] << 16);
        float hi = __uint_as_float(a[k] & 0xffff0000u) + __uint_as_float(b[k] & 0xffff0000u);
        res[k] = f2bfr(lo * inv) | (f2bfr(hi * inv) << 16);
    }
    *(uint4*)(AO + (size_t)row * 64 + d0) = *(uint4*)res;
}

// ---------------- output projection: out = AO @ Wob^T + bo ----------------
__global__ __launch_bounds__(256) void outproj_kernel(
    const unsigned short* __restrict__ AO, const unsigned short* __restrict__ Wob,
    const float* __restrict__ bo, float* __restrict__ out) {
    __shared__ __align__(16) unsigned short As[64 * 72];
    __shared__ __align__(16) unsigned short Bs[64 * 72];

    const int t = threadIdx.x, w = t >> 6, lane = t & 63, cl = lane & 15, quad = lane >> 4;
    const int e0 = blockIdx.x * 64;
    const int m0 = blockIdx.y * 64;
    const int srow = t >> 3, scol = (t & 7) * 8;

    float4v c[4];
#pragma unroll
    for (int nt = 0; nt < 4; ++nt) c[nt] = (float4v){0.f, 0.f, 0.f, 0.f};

    uint4 areg[2], breg[2];
#pragma unroll
    for (int p = 0; p < 2; ++p) {
        int i = srow + p * 32;
        int r = m0 + i, b = r >> 11, s = r & 2047;
        areg[p] = *(const uint4*)(AO + ((size_t)(b * 16 + 0) * SEQ + s) * 64 + scol);
        breg[p] = *(const uint4*)(Wob + (size_t)(e0 + i) * EMB + scol);
    }

    for (int hc = 0; hc < 16; ++hc) {
#pragma unroll
        for (int p = 0; p < 2; ++p) {
            int i = srow + p * 32;
            *(uint4*)(&As[i * 72 + scol]) = areg[p];
            *(uint4*)(&Bs[i * 72 + scol]) = breg[p];
        }
        __syncthreads();
        if (hc + 1 < 16) {
#pragma unroll
            for (int p = 0; p < 2; ++p) {
                int i = srow + p * 32;
                int r = m0 + i, b = r >> 11, s = r & 2047;
                areg[p] = *(const uint4*)(AO + ((size_t)(b * 16 + hc + 1) * SEQ + s) * 64 + scol);
                breg[p] = *(const uint4*)(Wob + (size_t)(e0 + i) * EMB + (hc + 1) * 64 + scol);
            }
        }
#pragma unroll
        for (int s2i = 0; s2i < 2; ++s2i) {
            short8 a = *(const short8*)(&As[(w * 16 + cl) * 72 + s2i * 32 + quad * 8]);
#pragma unroll
            for (int nt = 0; nt < 4; ++nt) {
                short8 bb = *(const short8*)(&Bs[(nt * 16 + cl) * 72 + s2i * 32 + quad * 8]);
                c[nt] = __builtin_amdgcn_mfma_f32_16x16x32_bf16(a, bb, c[nt], 0, 0, 0);
            }
        }
        __syncthreads();
    }

#pragma unroll
    for (int nt = 0; nt < 4; ++nt) {
        float bias = bo[e0 + nt * 16 + cl];
#pragma unroll
        for (int r = 0; r < 4; ++r) {
            int row = m0 + w * 16 + quad * 4 + r;
            out[(size_t)row * EMB + e0 + nt * 16 + cl] = c[nt][r] + bias;
        }
    }
}

extern "C" void kernel_launch(void* const* d_in, const int* in_sizes, int n_in,
                              void* d_out, int out_size, void* d_ws, size_t ws_size,
                              hipStream_t stream) {
    const float* values  = (const float*)d_in[0];
    const float* keys    = (const float*)d_in[1];
    const float* queries = (const float*)d_in[2];
    const float* Wv = (const float*)d_in[3];
    const float* Wk = (const float*)d_in[4];
    const float* Wq = (const float*)d_in[5];
    const float* Wo = (const float*)d_in[6];
    const float* bo = (const float*)d_in[7];
    float* out = (float*)d_out;

    char* ws = (char*)d_ws;
    unsigned short* Qp    = (unsigned short*)(ws);                 // 8 MB (B,H,S,D)
    unsigned short* Kp    = (unsigned short*)(ws + (8u  << 20));   // 8 MB (B,H,S,D)
    unsigned short* Vt    = (unsigned short*)(ws + (16u << 20));   // 8 MB (B,H,D,S slots)
    unsigned short* AO    = (unsigned short*)(ws + (24u << 20));   // 8 MB (B,H,S,D)
    unsigned short* Wob   = (unsigned short*)(ws + (32u << 20));   // 2 MB [e][k]
    unsigned short* Opart = (unsigned short*)(ws + (34u << 20));   // 16 MB (2 slices bf16)
    float*          Lpart = (float*)(ws + (50u << 20));            // 512 KB (2 slices f32)

    proj_kernel<<<dim3(SEQ / 64, BATCH * HEADS, 4), dim3(256), 0, stream>>>(
        values, keys, queries, Wv, Wk, Wq, Wo, Qp, Kp, Vt, Wob);
    attn_kernel<<<dim3(SEQ / 128, BATCH * HEADS, KSPLIT), dim3(256), 0, stream>>>(
        Qp, Kp, Vt, Opart, Lpart);
    norm_kernel<<<dim3((BATCH * HEADS * SEQ * 64 / 8) / 256), dim3(256), 0, stream>>>(
        Opart, Lpart, AO);
    outproj_kernel<<<dim3(EMB / 64, (BATCH * SEQ) / 64), dim3(256), 0, stream>>>(
        AO, Wob, bo, out);
}